// Round 7
// baseline (721.528 us; speedup 1.0000x reference)
//
#include <hip/hip_runtime.h>
#include <hip/hip_bf16.h>

#define BS   8192
#define DIM  768
#define TILE 128
#define BK   128
#define NIT  (DIM / BK)                 // 6
#define GRID ((BS / TILE) * (BS / TILE))  // 4096

typedef float f32x4 __attribute__((ext_vector_type(4)));
typedef int   i32x4 __attribute__((ext_vector_type(4)));
typedef int   i32x8 __attribute__((ext_vector_type(8)));

__device__ __forceinline__ void async16(const void* g, void* l) {
    __builtin_amdgcn_global_load_lds(
        (const __attribute__((address_space(1))) unsigned int*)g,
        (__attribute__((address_space(3))) unsigned int*)l,
        16, 0, 0);
}

// One wave per row: L2-norm both embeddings, emit fp8 e4m3, diag sim in fp32.
// Blocks 0..63 also zero rowsum/colsum; block 64 zeroes the done-counter.
__global__ __launch_bounds__(256) void normalize_kernel(
    const float* __restrict__ text, const float* __restrict__ ctr,
    unsigned char* __restrict__ tq, unsigned char* __restrict__ cq,
    float* __restrict__ sim, float* __restrict__ rowsum, float* __restrict__ colsum,
    unsigned int* __restrict__ cnt) {
    if (blockIdx.x < 64) {
        const int i = blockIdx.x * 256 + threadIdx.x;   // covers 16384 = 2*BS
        rowsum[i] = 0.f;
        colsum[i] = 0.f;
    }
    if (blockIdx.x == 64 && threadIdx.x == 0) *cnt = 0u;
    const int lane = threadIdx.x & 63;
    const int row  = blockIdx.x * 4 + (threadIdx.x >> 6);
    const size_t base = (size_t)row * DIM;

    float4 t[3], c[3];
    float st = 0.f, sc = 0.f, sd = 0.f;
#pragma unroll
    for (int i = 0; i < 3; ++i) {
        t[i] = *(const float4*)&text[base + lane * 4 + i * 256];
        c[i] = *(const float4*)&ctr [base + lane * 4 + i * 256];
        st += t[i].x*t[i].x + t[i].y*t[i].y + t[i].z*t[i].z + t[i].w*t[i].w;
        sc += c[i].x*c[i].x + c[i].y*c[i].y + c[i].z*c[i].z + c[i].w*c[i].w;
        sd += t[i].x*c[i].x + t[i].y*c[i].y + t[i].z*c[i].z + t[i].w*c[i].w;
    }
#pragma unroll
    for (int off = 1; off < 64; off <<= 1) {
        st += __shfl_xor(st, off);
        sc += __shfl_xor(sc, off);
        sd += __shfl_xor(sd, off);
    }
    const float invt = 1.0f / fmaxf(sqrtf(st), 1e-8f);
    const float invc = 1.0f / fmaxf(sqrtf(sc), 1e-8f);
#pragma unroll
    for (int i = 0; i < 3; ++i) {
        unsigned int wt = (unsigned int)__builtin_amdgcn_cvt_pk_fp8_f32(t[i].x * invt, t[i].y * invt, 0, false);
        wt = (unsigned int)__builtin_amdgcn_cvt_pk_fp8_f32(t[i].z * invt, t[i].w * invt, (int)wt, true);
        unsigned int wcq = (unsigned int)__builtin_amdgcn_cvt_pk_fp8_f32(c[i].x * invc, c[i].y * invc, 0, false);
        wcq = (unsigned int)__builtin_amdgcn_cvt_pk_fp8_f32(c[i].z * invc, c[i].w * invc, (int)wcq, true);
        *(unsigned int*)&tq[base + lane * 4 + i * 256] = wt;
        *(unsigned int*)&cq[base + lane * 4 + i * 256] = wcq;
    }
    if (lane == 0) sim[row] = sd * invt * invc;
}

// MX-scaled fp8 GEMM, R4 shape (128x128 tile, BK=128, 512 thr / 8 waves 2x4,
// acc 32 regs -> 44 VGPR baseline) + ONE-barrier double-buffered K-loop:
//   barrier -> prefetch k+1 into buf^1 (vmcnt) -> compute k from buf^0 (lgkm).
// The compiler's vmcnt(0)-before-barrier then drains loads that had a full
// compute phase to land (cheap), instead of serializing fresh loads (R3/R4's
// ~6000 cy/iter chain). Buffer-reuse hazard: stage(k+1) overwrites the buffer
// last read in compute(k-1); the barrier at top of iter k orders them.
// LDS 64 KB/block -> 2 blocks/CU (128 KB). Swizzle scheme: verified
// conflict-free (SQ_LDS_BANK_CONFLICT == 0, R3-R5).
// Last block (agent-scope counter) computes the final loss (R5/R6-verified).
__global__ __launch_bounds__(512, 4) void gemm_lse_kernel(
    const unsigned char* __restrict__ tq, const unsigned char* __restrict__ cq,
    float* __restrict__ rowsum, float* __restrict__ colsum,
    const float* __restrict__ sim, unsigned int* __restrict__ cnt,
    float* __restrict__ out) {
    __shared__ char lds[2 * 32768];   // [buf][A 16K | B 16K] = 64 KB

    const int tid = threadIdx.x;

    // XCD-banded swizzle: XCD x owns tile-rows [8x, 8x+8), sweeping columns.
    const int bid = blockIdx.x;
    const int xcd = bid & 7, idx = bid >> 3;
    const int tileCol = idx >> 3, rowInBand = idx & 7;
    const int rowBase = (xcd * 8 + rowInBand) * TILE;
    const int colBase = tileCol * TILE;

    const int wave = tid >> 6, lane = tid & 63;
    const int wr = wave >> 2, wc = wave & 3;        // 2x4 wave grid: 64 rows x 32 cols
    const int quad = lane >> 4, l16 = lane & 15;

    // Staging: per buffer, A = 1024 16B chunks ([kc(4)][row(128)][32B], halves
    // swizzled by kc&1), B identical at +16K. Thread owns chunks tid, tid+512.
    int goff[2], lofs[2];
#pragma unroll
    for (int i = 0; i < 2; ++i) {
        const int p  = tid + i * 512;
        const int kc = p >> 8;
        const int row = (p >> 1) & 127;
        const int hl  = (p & 1) ^ (kc & 1);
        goff[i] = row * DIM + kc * 32 + hl * 16;
        lofs[i] = p * 16;
    }
    const unsigned char* gA = tq + (size_t)rowBase * DIM;
    const unsigned char* gB = cq + (size_t)colBase * DIM;

    // Fragment addressing: lane (quad,l16) reads kc=quad plane of its row;
    // physical half = logical half ^ (quad&1). kc plane stride = 4096 B.
    const int sw = quad & 1;
    int aoff[4], boff[2];
#pragma unroll
    for (int mt = 0; mt < 4; ++mt) aoff[mt] = quad * 4096 + (wr * 64 + mt * 16 + l16) * 32;
#pragma unroll
    for (int nt = 0; nt < 2; ++nt) boff[nt] = quad * 4096 + (wc * 32 + nt * 16 + l16) * 32;

    f32x4 acc[4][2];
#pragma unroll
    for (int mt = 0; mt < 4; ++mt)
#pragma unroll
        for (int nt = 0; nt < 2; ++nt)
            acc[mt][nt] = (f32x4){0.f, 0.f, 0.f, 0.f};

    // Prologue: stage K-chunk 0 into buffer 0.
#pragma unroll
    for (int i = 0; i < 2; ++i) {
        async16(gA + goff[i], lds + lofs[i]);
        async16(gB + goff[i], lds + 16384 + lofs[i]);
    }

    for (int it = 0; it < NIT; ++it) {
        __syncthreads();   // drains my stage(it) loads (they had a full compute
                           // phase to land) and protects buf^1 reuse
        if (it + 1 < NIT) {
            const int k0 = (it + 1) * BK;
            char* nb = lds + ((it + 1) & 1) * 32768;
#pragma unroll
            for (int i = 0; i < 2; ++i) {
                async16(gA + goff[i] + k0, nb + lofs[i]);
                async16(gB + goff[i] + k0, nb + 16384 + lofs[i]);
            }
        }
        const char* bA = lds + (it & 1) * 32768;
        const char* bB = bA + 16384;

        i32x8 bfr[2];
#pragma unroll
        for (int nt = 0; nt < 2; ++nt) {
            i32x4 lo = *(const i32x4*)(bB + boff[nt] + sw * 16);
            i32x4 hi = *(const i32x4*)(bB + boff[nt] + (sw ^ 1) * 16);
            bfr[nt] = __builtin_shufflevector(lo, hi, 0, 1, 2, 3, 4, 5, 6, 7);
        }
#pragma unroll
        for (int mt = 0; mt < 4; ++mt) {
            i32x4 lo = *(const i32x4*)(bA + aoff[mt] + sw * 16);
            i32x4 hi = *(const i32x4*)(bA + aoff[mt] + (sw ^ 1) * 16);
            i32x8 af = __builtin_shufflevector(lo, hi, 0, 1, 2, 3, 4, 5, 6, 7);
#pragma unroll
            for (int nt = 0; nt < 2; ++nt)
                acc[mt][nt] = __builtin_amdgcn_mfma_scale_f32_16x16x128_f8f6f4(
                    af, bfr[nt], acc[mt][nt], 0, 0, 0, 127, 0, 127);
        }
        // no trailing barrier: next iteration's top barrier is the only one
    }

    // Epilogue. D layout: col = l16 (ctr idx), row = quad*4 + reg (text idx).
    float rp[4][4];   // [mt][reg] partials over this wave's 32 cols
    float cp[2];      // [nt] partials over this wave's 64 rows
#pragma unroll
    for (int mt = 0; mt < 4; ++mt)
#pragma unroll
        for (int r = 0; r < 4; ++r) rp[mt][r] = 0.f;
#pragma unroll
    for (int nt = 0; nt < 2; ++nt) cp[nt] = 0.f;

#pragma unroll
    for (int mt = 0; mt < 4; ++mt)
#pragma unroll
        for (int nt = 0; nt < 2; ++nt)
#pragma unroll
            for (int r = 0; r < 4; ++r) {
                const float e = __expf(acc[mt][nt][r]);   // S in [-1,1]: no max needed
                rp[mt][r] += e;
                cp[nt]    += e;
            }

#pragma unroll
    for (int mt = 0; mt < 4; ++mt)
#pragma unroll
        for (int r = 0; r < 4; ++r) {
            float v = rp[mt][r];
            v += __shfl_xor(v, 1);
            v += __shfl_xor(v, 2);
            v += __shfl_xor(v, 4);
            v += __shfl_xor(v, 8);
            if (l16 == 0)
                atomicAdd(&rowsum[rowBase + wr * 64 + mt * 16 + quad * 4 + r], v);
        }
#pragma unroll
    for (int nt = 0; nt < 2; ++nt) {
        float v = cp[nt];
        v += __shfl_xor(v, 16);
        v += __shfl_xor(v, 32);
        if (quad == 0)
            atomicAdd(&colsum[colBase + wc * 32 + nt * 16 + l16], v);
    }

    // ---- Fused finalize: last block to finish reduces the 16K sums. ----
    float* redf = (float*)lds;
    unsigned int* flagp = (unsigned int*)(lds + 128);
    __syncthreads();
    if (tid == 0) {
        unsigned int old = __hip_atomic_fetch_add(cnt, 1u, __ATOMIC_ACQ_REL,
                                                  __HIP_MEMORY_SCOPE_AGENT);
        *flagp = (old == GRID - 1) ? 1u : 0u;
    }
    __syncthreads();
    if (*flagp) {
        float a = 0.f;
        for (int j = tid; j < BS; j += 512) {
            const float rs = __hip_atomic_load(&rowsum[j], __ATOMIC_RELAXED,
                                               __HIP_MEMORY_SCOPE_AGENT);
            const float cs = __hip_atomic_load(&colsum[j], __ATOMIC_RELAXED,
                                               __HIP_MEMORY_SCOPE_AGENT);
            a += __logf(rs) + __logf(cs) - 2.f * sim[j];
        }
#pragma unroll
        for (int off = 1; off < 64; off <<= 1) a += __shfl_xor(a, off);
        if (lane == 0) redf[wave] = a;
        __syncthreads();
        if (tid == 0) {
            float s = 0.f;
#pragma unroll
            for (int w = 0; w < 8; ++w) s += redf[w];
            out[0] = s / (float)BS;
        }
    }
}

extern "C" void kernel_launch(void* const* d_in, const int* in_sizes, int n_in,
                              void* d_out, int out_size, void* d_ws, size_t ws_size,
                              hipStream_t stream) {
    const float* text = (const float*)d_in[0];
    const float* ctr  = (const float*)d_in[1];

    char* ws = (char*)d_ws;
    const size_t embBytes = (size_t)BS * DIM;   // fp8: 6,291,456 bytes each
    unsigned char* tq = (unsigned char*)ws;
    unsigned char* cq = (unsigned char*)(ws + embBytes);
    float* sim    = (float*)(ws + 2 * embBytes);
    float* rowsum = (float*)(ws + 2 * embBytes + BS * sizeof(float));
    float* colsum = (float*)(ws + 2 * embBytes + 2 * BS * sizeof(float));
    unsigned int* cnt = (unsigned int*)(ws + 2 * embBytes + 3 * BS * sizeof(float));

    normalize_kernel<<<BS / 4, 256, 0, stream>>>(text, ctr, tq, cq, sim,
                                                 rowsum, colsum, cnt);

    gemm_lse_kernel<<<GRID, 512, 0, stream>>>(tq, cq, rowsum, colsum, sim,
                                              cnt, (float*)d_out);
}

// Round 8
// 560.205 us; speedup vs baseline: 1.2880x; 1.2880x over previous
//
#include <hip/hip_runtime.h>
#include <hip/hip_bf16.h>

#define BS   8192
#define DIM  768
#define TILE 128
#define BK   128
#define NIT  (DIM / BK)                 // 6
#define GRID ((BS / TILE) * (BS / TILE))  // 4096

typedef float f32x4 __attribute__((ext_vector_type(4)));
typedef int   i32x4 __attribute__((ext_vector_type(4)));
typedef int   i32x8 __attribute__((ext_vector_type(8)));

__device__ __forceinline__ void async16(const void* g, void* l) {
    __builtin_amdgcn_global_load_lds(
        (const __attribute__((address_space(1))) unsigned int*)g,
        (__attribute__((address_space(3))) unsigned int*)l,
        16, 0, 0);
}

// One wave per row: L2-norm both embeddings, emit fp8 e4m3, diag sim in fp32.
// Blocks 0..63 also zero rowsum/colsum (replaces a memset dispatch).
__global__ __launch_bounds__(256) void normalize_kernel(
    const float* __restrict__ text, const float* __restrict__ ctr,
    unsigned char* __restrict__ tq, unsigned char* __restrict__ cq,
    float* __restrict__ sim, float* __restrict__ rowsum, float* __restrict__ colsum) {
    if (blockIdx.x < 64) {
        const int i = blockIdx.x * 256 + threadIdx.x;   // covers 16384 = 2*BS
        rowsum[i] = 0.f;
        colsum[i] = 0.f;
    }
    const int lane = threadIdx.x & 63;
    const int row  = blockIdx.x * 4 + (threadIdx.x >> 6);
    const size_t base = (size_t)row * DIM;

    float4 t[3], c[3];
    float st = 0.f, sc = 0.f, sd = 0.f;
#pragma unroll
    for (int i = 0; i < 3; ++i) {
        t[i] = *(const float4*)&text[base + lane * 4 + i * 256];
        c[i] = *(const float4*)&ctr [base + lane * 4 + i * 256];
        st += t[i].x*t[i].x + t[i].y*t[i].y + t[i].z*t[i].z + t[i].w*t[i].w;
        sc += c[i].x*c[i].x + c[i].y*c[i].y + c[i].z*c[i].z + c[i].w*c[i].w;
        sd += t[i].x*c[i].x + t[i].y*c[i].y + t[i].z*c[i].z + t[i].w*c[i].w;
    }
#pragma unroll
    for (int off = 1; off < 64; off <<= 1) {
        st += __shfl_xor(st, off);
        sc += __shfl_xor(sc, off);
        sd += __shfl_xor(sd, off);
    }
    const float invt = 1.0f / fmaxf(sqrtf(st), 1e-8f);
    const float invc = 1.0f / fmaxf(sqrtf(sc), 1e-8f);
#pragma unroll
    for (int i = 0; i < 3; ++i) {
        unsigned int wt = (unsigned int)__builtin_amdgcn_cvt_pk_fp8_f32(t[i].x * invt, t[i].y * invt, 0, false);
        wt = (unsigned int)__builtin_amdgcn_cvt_pk_fp8_f32(t[i].z * invt, t[i].w * invt, (int)wt, true);
        unsigned int wcq = (unsigned int)__builtin_amdgcn_cvt_pk_fp8_f32(c[i].x * invc, c[i].y * invc, 0, false);
        wcq = (unsigned int)__builtin_amdgcn_cvt_pk_fp8_f32(c[i].z * invc, c[i].w * invc, (int)wcq, true);
        *(unsigned int*)&tq[base + lane * 4 + i * 256] = wt;
        *(unsigned int*)&cq[base + lane * 4 + i * 256] = wcq;
    }
    if (lane == 0) sim[row] = sd * invt * invc;
}

// MX-scaled fp8 GEMM, 128x128 tile, BK=128, 512 thr / 8 waves (2x4),
// ONE-barrier double-buffered K-loop:
//   barrier -> prefetch k+1 into buf^1 (vmcnt) -> compute k from buf^0 (lgkm).
// The compiler's vmcnt(0)-before-barrier drains loads that had a full compute
// phase (~2000 cy) to land, instead of serializing fresh loads.
// NOTE: no agent-scope ACQ_REL atomics anywhere in this kernel — R5-R7 showed
// the fused-finalize release/acquire emits buffer_wbl2/buffer_inv per block,
// flushing the XCD L2 4096x and turning tile re-reads into HBM streams
// (FETCH 854 MB / WRITE 1.26 GB in R7). Plain atomicAdd (TCC-side) is safe.
// LDS 64 KB/block -> 2 blocks/CU. Swizzle verified conflict-free (R3-R7).
__global__ __launch_bounds__(512, 4) void gemm_lse_kernel(
    const unsigned char* __restrict__ tq, const unsigned char* __restrict__ cq,
    float* __restrict__ rowsum, float* __restrict__ colsum) {
    __shared__ char lds[2 * 32768];   // [buf][A 16K | B 16K] = 64 KB

    const int tid = threadIdx.x;

    // XCD-banded swizzle: XCD x owns tile-rows [8x, 8x+8), sweeping columns.
    const int bid = blockIdx.x;
    const int xcd = bid & 7, idx = bid >> 3;
    const int tileCol = idx >> 3, rowInBand = idx & 7;
    const int rowBase = (xcd * 8 + rowInBand) * TILE;
    const int colBase = tileCol * TILE;

    const int wave = tid >> 6, lane = tid & 63;
    const int wr = wave >> 2, wc = wave & 3;        // 2x4 wave grid: 64 rows x 32 cols
    const int quad = lane >> 4, l16 = lane & 15;

    // Staging: per buffer, A = 1024 16B chunks ([kc(4)][row(128)][32B], halves
    // swizzled by kc&1), B identical at +16K. Thread owns chunks tid, tid+512.
    int goff[2], lofs[2];
#pragma unroll
    for (int i = 0; i < 2; ++i) {
        const int p  = tid + i * 512;
        const int kc = p >> 8;
        const int row = (p >> 1) & 127;
        const int hl  = (p & 1) ^ (kc & 1);
        goff[i] = row * DIM + kc * 32 + hl * 16;
        lofs[i] = p * 16;
    }
    const unsigned char* gA = tq + (size_t)rowBase * DIM;
    const unsigned char* gB = cq + (size_t)colBase * DIM;

    // Fragment addressing: lane (quad,l16) reads kc=quad plane of its row;
    // physical half = logical half ^ (quad&1). kc plane stride = 4096 B.
    const int sw = quad & 1;
    int aoff[4], boff[2];
#pragma unroll
    for (int mt = 0; mt < 4; ++mt) aoff[mt] = quad * 4096 + (wr * 64 + mt * 16 + l16) * 32;
#pragma unroll
    for (int nt = 0; nt < 2; ++nt) boff[nt] = quad * 4096 + (wc * 32 + nt * 16 + l16) * 32;

    f32x4 acc[4][2];
#pragma unroll
    for (int mt = 0; mt < 4; ++mt)
#pragma unroll
        for (int nt = 0; nt < 2; ++nt)
            acc[mt][nt] = (f32x4){0.f, 0.f, 0.f, 0.f};

    // Prologue: stage K-chunk 0 into buffer 0.
#pragma unroll
    for (int i = 0; i < 2; ++i) {
        async16(gA + goff[i], lds + lofs[i]);
        async16(gB + goff[i], lds + 16384 + lofs[i]);
    }

    for (int it = 0; it < NIT; ++it) {
        __syncthreads();   // drains stage(it) loads (they had a full compute
                           // phase to land) and protects buf^1 reuse
        if (it + 1 < NIT) {
            const int k0 = (it + 1) * BK;
            char* nb = lds + ((it + 1) & 1) * 32768;
#pragma unroll
            for (int i = 0; i < 2; ++i) {
                async16(gA + goff[i] + k0, nb + lofs[i]);
                async16(gB + goff[i] + k0, nb + 16384 + lofs[i]);
            }
        }
        const char* bA = lds + (it & 1) * 32768;
        const char* bB = bA + 16384;

        i32x8 bfr[2];
#pragma unroll
        for (int nt = 0; nt < 2; ++nt) {
            i32x4 lo = *(const i32x4*)(bB + boff[nt] + sw * 16);
            i32x4 hi = *(const i32x4*)(bB + boff[nt] + (sw ^ 1) * 16);
            bfr[nt] = __builtin_shufflevector(lo, hi, 0, 1, 2, 3, 4, 5, 6, 7);
        }
#pragma unroll
        for (int mt = 0; mt < 4; ++mt) {
            i32x4 lo = *(const i32x4*)(bA + aoff[mt] + sw * 16);
            i32x4 hi = *(const i32x4*)(bA + aoff[mt] + (sw ^ 1) * 16);
            i32x8 af = __builtin_shufflevector(lo, hi, 0, 1, 2, 3, 4, 5, 6, 7);
#pragma unroll
            for (int nt = 0; nt < 2; ++nt)
                acc[mt][nt] = __builtin_amdgcn_mfma_scale_f32_16x16x128_f8f6f4(
                    af, bfr[nt], acc[mt][nt], 0, 0, 0, 127, 0, 127);
        }
        // no trailing barrier: next iteration's top barrier is the only one
    }

    // Epilogue. D layout: col = l16 (ctr idx), row = quad*4 + reg (text idx).
    float rp[4][4];   // [mt][reg] partials over this wave's 32 cols
    float cp[2];      // [nt] partials over this wave's 64 rows
#pragma unroll
    for (int mt = 0; mt < 4; ++mt)
#pragma unroll
        for (int r = 0; r < 4; ++r) rp[mt][r] = 0.f;
#pragma unroll
    for (int nt = 0; nt < 2; ++nt) cp[nt] = 0.f;

#pragma unroll
    for (int mt = 0; mt < 4; ++mt)
#pragma unroll
        for (int nt = 0; nt < 2; ++nt)
#pragma unroll
            for (int r = 0; r < 4; ++r) {
                const float e = __expf(acc[mt][nt][r]);   // S in [-1,1]: no max needed
                rp[mt][r] += e;
                cp[nt]    += e;
            }

#pragma unroll
    for (int mt = 0; mt < 4; ++mt)
#pragma unroll
        for (int r = 0; r < 4; ++r) {
            float v = rp[mt][r];
            v += __shfl_xor(v, 1);
            v += __shfl_xor(v, 2);
            v += __shfl_xor(v, 4);
            v += __shfl_xor(v, 8);
            if (l16 == 0)
                atomicAdd(&rowsum[rowBase + wr * 64 + mt * 16 + quad * 4 + r], v);
        }
#pragma unroll
    for (int nt = 0; nt < 2; ++nt) {
        float v = cp[nt];
        v += __shfl_xor(v, 16);
        v += __shfl_xor(v, 32);
        if (quad == 0)
            atomicAdd(&colsum[colBase + wc * 32 + nt * 16 + l16], v);
    }
}

__global__ __launch_bounds__(1024) void finalize_kernel(
    const float* __restrict__ rowsum, const float* __restrict__ colsum,
    const float* __restrict__ sim, float* __restrict__ out) {
    const int tid = threadIdx.x;
    float acc = 0.f;
#pragma unroll
    for (int i = 0; i < 2; ++i) {
        const int j = (tid + i * 1024) * 4;
        float4 rs = *(const float4*)&rowsum[j];
        float4 cs = *(const float4*)&colsum[j];
        float4 sm = *(const float4*)&sim[j];
        acc += __logf(rs.x) + __logf(rs.y) + __logf(rs.z) + __logf(rs.w);
        acc += __logf(cs.x) + __logf(cs.y) + __logf(cs.z) + __logf(cs.w);
        acc -= 2.f * (sm.x + sm.y + sm.z + sm.w);
    }
#pragma unroll
    for (int off = 1; off < 64; off <<= 1) acc += __shfl_xor(acc, off);
    __shared__ float red[16];
    const int wave = tid >> 6, lane = tid & 63;
    if (lane == 0) red[wave] = acc;
    __syncthreads();
    if (tid == 0) {
        float s = 0.f;
#pragma unroll
        for (int w = 0; w < 16; ++w) s += red[w];
        out[0] = s / (float)BS;
    }
}

extern "C" void kernel_launch(void* const* d_in, const int* in_sizes, int n_in,
                              void* d_out, int out_size, void* d_ws, size_t ws_size,
                              hipStream_t stream) {
    const float* text = (const float*)d_in[0];
    const float* ctr  = (const float*)d_in[1];

    char* ws = (char*)d_ws;
    const size_t embBytes = (size_t)BS * DIM;   // fp8: 6,291,456 bytes each
    unsigned char* tq = (unsigned char*)ws;
    unsigned char* cq = (unsigned char*)(ws + embBytes);
    float* sim    = (float*)(ws + 2 * embBytes);
    float* rowsum = (float*)(ws + 2 * embBytes + BS * sizeof(float));
    float* colsum = (float*)(ws + 2 * embBytes + 2 * BS * sizeof(float));

    normalize_kernel<<<BS / 4, 256, 0, stream>>>(text, ctr, tq, cq, sim,
                                                 rowsum, colsum);

    gemm_lse_kernel<<<GRID, 512, 0, stream>>>(tq, cq, rowsum, colsum);

    finalize_kernel<<<1, 1024, 0, stream>>>(rowsum, colsum, sim, (float*)d_out);
}

// Round 9
// 233.432 us; speedup vs baseline: 3.0910x; 2.3999x over previous
//
#include <hip/hip_runtime.h>
#include <hip/hip_bf16.h>

#define BS   8192
#define DIM  768
#define TILE 128
#define BK   128
#define NIT  (DIM / BK)                 // 6
#define GRID ((BS / TILE) * (BS / TILE))  // 4096

typedef float f32x4 __attribute__((ext_vector_type(4)));
typedef int   i32x4 __attribute__((ext_vector_type(4)));
typedef int   i32x8 __attribute__((ext_vector_type(8)));

__device__ __forceinline__ void async16(const void* g, void* l) {
    __builtin_amdgcn_global_load_lds(
        (const __attribute__((address_space(1))) unsigned int*)g,
        (__attribute__((address_space(3))) unsigned int*)l,
        16, 0, 0);
}

// One wave per row: L2-norm both embeddings, emit fp8 e4m3, diag sim in fp32.
// Blocks 0..63 also zero rowsum/colsum (replaces a memset dispatch).
__global__ __launch_bounds__(256) void normalize_kernel(
    const float* __restrict__ text, const float* __restrict__ ctr,
    unsigned char* __restrict__ tq, unsigned char* __restrict__ cq,
    float* __restrict__ sim, float* __restrict__ rowsum, float* __restrict__ colsum) {
    if (blockIdx.x < 64) {
        const int i = blockIdx.x * 256 + threadIdx.x;   // covers 16384 = 2*BS
        rowsum[i] = 0.f;
        colsum[i] = 0.f;
    }
    const int lane = threadIdx.x & 63;
    const int row  = blockIdx.x * 4 + (threadIdx.x >> 6);
    const size_t base = (size_t)row * DIM;

    float4 t[3], c[3];
    float st = 0.f, sc = 0.f, sd = 0.f;
#pragma unroll
    for (int i = 0; i < 3; ++i) {
        t[i] = *(const float4*)&text[base + lane * 4 + i * 256];
        c[i] = *(const float4*)&ctr [base + lane * 4 + i * 256];
        st += t[i].x*t[i].x + t[i].y*t[i].y + t[i].z*t[i].z + t[i].w*t[i].w;
        sc += c[i].x*c[i].x + c[i].y*c[i].y + c[i].z*c[i].z + c[i].w*c[i].w;
        sd += t[i].x*c[i].x + t[i].y*c[i].y + t[i].z*c[i].z + t[i].w*c[i].w;
    }
#pragma unroll
    for (int off = 1; off < 64; off <<= 1) {
        st += __shfl_xor(st, off);
        sc += __shfl_xor(sc, off);
        sd += __shfl_xor(sd, off);
    }
    const float invt = 1.0f / fmaxf(sqrtf(st), 1e-8f);
    const float invc = 1.0f / fmaxf(sqrtf(sc), 1e-8f);
#pragma unroll
    for (int i = 0; i < 3; ++i) {
        unsigned int wt = (unsigned int)__builtin_amdgcn_cvt_pk_fp8_f32(t[i].x * invt, t[i].y * invt, 0, false);
        wt = (unsigned int)__builtin_amdgcn_cvt_pk_fp8_f32(t[i].z * invt, t[i].w * invt, (int)wt, true);
        unsigned int wcq = (unsigned int)__builtin_amdgcn_cvt_pk_fp8_f32(c[i].x * invc, c[i].y * invc, 0, false);
        wcq = (unsigned int)__builtin_amdgcn_cvt_pk_fp8_f32(c[i].z * invc, c[i].w * invc, (int)wcq, true);
        *(unsigned int*)&tq[base + lane * 4 + i * 256] = wt;
        *(unsigned int*)&cq[base + lane * 4 + i * 256] = wcq;
    }
    if (lane == 0) sim[row] = sd * invt * invc;
}

// MX-scaled fp8 GEMM, 128x128 tile, BK=128, 512 thr / 8 waves (2x4),
// ONE-barrier double-buffered K-loop:
//   barrier -> prefetch k+1 into buf^1 (vmcnt) -> compute k from buf^0 (lgkm).
//
// LAUNCH BOUNDS WARNING (R7/R8 post-mortem): (512,4) imposed a 64-VGPR cap
// (observed: VGPR_Count pinned at exactly 64, per-iteration acc spill/restore
// -> 1.2 GB scratch WRITE_SIZE + all L2 locality evicted, 495 us). (512,2)
// caps at 128; this kernel needs ~80. Do not tighten without checking
// WRITE_SIZE and VGPR_Count.
// LDS 64 KB/block -> 2 blocks/CU (LDS-limited). Swizzle conflict-free (R3-R8).
__global__ __launch_bounds__(512, 2) void gemm_lse_kernel(
    const unsigned char* __restrict__ tq, const unsigned char* __restrict__ cq,
    float* __restrict__ rowsum, float* __restrict__ colsum) {
    __shared__ char lds[2 * 32768];   // [buf][A 16K | B 16K] = 64 KB

    const int tid = threadIdx.x;

    // XCD-banded swizzle: XCD x owns tile-rows [8x, 8x+8), sweeping columns.
    const int bid = blockIdx.x;
    const int xcd = bid & 7, idx = bid >> 3;
    const int tileCol = idx >> 3, rowInBand = idx & 7;
    const int rowBase = (xcd * 8 + rowInBand) * TILE;
    const int colBase = tileCol * TILE;

    const int wave = tid >> 6, lane = tid & 63;
    const int wr = wave >> 2, wc = wave & 3;        // 2x4 wave grid: 64 rows x 32 cols
    const int quad = lane >> 4, l16 = lane & 15;

    // Staging: per buffer, A = 1024 16B chunks ([kc(4)][row(128)][32B], halves
    // swizzled by kc&1), B identical at +16K. Thread owns chunks tid, tid+512.
    int goff[2], lofs[2];
#pragma unroll
    for (int i = 0; i < 2; ++i) {
        const int p  = tid + i * 512;
        const int kc = p >> 8;
        const int row = (p >> 1) & 127;
        const int hl  = (p & 1) ^ (kc & 1);
        goff[i] = row * DIM + kc * 32 + hl * 16;
        lofs[i] = p * 16;
    }
    const unsigned char* gA = tq + (size_t)rowBase * DIM;
    const unsigned char* gB = cq + (size_t)colBase * DIM;

    // Fragment addressing: lane (quad,l16) reads kc=quad plane of its row;
    // physical half = logical half ^ (quad&1). kc plane stride = 4096 B.
    const int sw = quad & 1;
    int aoff[4], boff[2];
#pragma unroll
    for (int mt = 0; mt < 4; ++mt) aoff[mt] = quad * 4096 + (wr * 64 + mt * 16 + l16) * 32;
#pragma unroll
    for (int nt = 0; nt < 2; ++nt) boff[nt] = quad * 4096 + (wc * 32 + nt * 16 + l16) * 32;

    f32x4 acc[4][2];
#pragma unroll
    for (int mt = 0; mt < 4; ++mt)
#pragma unroll
        for (int nt = 0; nt < 2; ++nt)
            acc[mt][nt] = (f32x4){0.f, 0.f, 0.f, 0.f};

    // Prologue: stage K-chunk 0 into buffer 0.
#pragma unroll
    for (int i = 0; i < 2; ++i) {
        async16(gA + goff[i], lds + lofs[i]);
        async16(gB + goff[i], lds + 16384 + lofs[i]);
    }

    for (int it = 0; it < NIT; ++it) {
        __syncthreads();   // drains stage(it) loads (they had a full compute
                           // phase to land) and protects buf^1 reuse
        if (it + 1 < NIT) {
            const int k0 = (it + 1) * BK;
            char* nb = lds + ((it + 1) & 1) * 32768;
#pragma unroll
            for (int i = 0; i < 2; ++i) {
                async16(gA + goff[i] + k0, nb + lofs[i]);
                async16(gB + goff[i] + k0, nb + 16384 + lofs[i]);
            }
        }
        const char* bA = lds + (it & 1) * 32768;
        const char* bB = bA + 16384;

        i32x8 bfr[2];
#pragma unroll
        for (int nt = 0; nt < 2; ++nt) {
            i32x4 lo = *(const i32x4*)(bB + boff[nt] + sw * 16);
            i32x4 hi = *(const i32x4*)(bB + boff[nt] + (sw ^ 1) * 16);
            bfr[nt] = __builtin_shufflevector(lo, hi, 0, 1, 2, 3, 4, 5, 6, 7);
        }
#pragma unroll
        for (int mt = 0; mt < 4; ++mt) {
            i32x4 lo = *(const i32x4*)(bA + aoff[mt] + sw * 16);
            i32x4 hi = *(const i32x4*)(bA + aoff[mt] + (sw ^ 1) * 16);
            i32x8 af = __builtin_shufflevector(lo, hi, 0, 1, 2, 3, 4, 5, 6, 7);
#pragma unroll
            for (int nt = 0; nt < 2; ++nt)
                acc[mt][nt] = __builtin_amdgcn_mfma_scale_f32_16x16x128_f8f6f4(
                    af, bfr[nt], acc[mt][nt], 0, 0, 0, 127, 0, 127);
        }
        // no trailing barrier: next iteration's top barrier is the only one
    }

    // Epilogue. D layout: col = l16 (ctr idx), row = quad*4 + reg (text idx).
    float rp[4][4];   // [mt][reg] partials over this wave's 32 cols
    float cp[2];      // [nt] partials over this wave's 64 rows
#pragma unroll
    for (int mt = 0; mt < 4; ++mt)
#pragma unroll
        for (int r = 0; r < 4; ++r) rp[mt][r] = 0.f;
#pragma unroll
    for (int nt = 0; nt < 2; ++nt) cp[nt] = 0.f;

#pragma unroll
    for (int mt = 0; mt < 4; ++mt)
#pragma unroll
        for (int nt = 0; nt < 2; ++nt)
#pragma unroll
            for (int r = 0; r < 4; ++r) {
                const float e = __expf(acc[mt][nt][r]);   // S in [-1,1]: no max needed
                rp[mt][r] += e;
                cp[nt]    += e;
            }

#pragma unroll
    for (int mt = 0; mt < 4; ++mt)
#pragma unroll
        for (int r = 0; r < 4; ++r) {
            float v = rp[mt][r];
            v += __shfl_xor(v, 1);
            v += __shfl_xor(v, 2);
            v += __shfl_xor(v, 4);
            v += __shfl_xor(v, 8);
            if (l16 == 0)
                atomicAdd(&rowsum[rowBase + wr * 64 + mt * 16 + quad * 4 + r], v);
        }
#pragma unroll
    for (int nt = 0; nt < 2; ++nt) {
        float v = cp[nt];
        v += __shfl_xor(v, 16);
        v += __shfl_xor(v, 32);
        if (quad == 0)
            atomicAdd(&colsum[colBase + wc * 32 + nt * 16 + l16], v);
    }
}

__global__ __launch_bounds__(1024) void finalize_kernel(
    const float* __restrict__ rowsum, const float* __restrict__ colsum,
    const float* __restrict__ sim, float* __restrict__ out) {
    const int tid = threadIdx.x;
    float acc = 0.f;
#pragma unroll
    for (int i = 0; i < 2; ++i) {
        const int j = (tid + i * 1024) * 4;
        float4 rs = *(const float4*)&rowsum[j];
        float4 cs = *(const float4*)&colsum[j];
        float4 sm = *(const float4*)&sim[j];
        acc += __logf(rs.x) + __logf(rs.y) + __logf(rs.z) + __logf(rs.w);
        acc += __logf(cs.x) + __logf(cs.y) + __logf(cs.z) + __logf(cs.w);
        acc -= 2.f * (sm.x + sm.y + sm.z + sm.w);
    }
#pragma unroll
    for (int off = 1; off < 64; off <<= 1) acc += __shfl_xor(acc, off);
    __shared__ float red[16];
    const int wave = tid >> 6, lane = tid & 63;
    if (lane == 0) red[wave] = acc;
    __syncthreads();
    if (tid == 0) {
        float s = 0.f;
#pragma unroll
        for (int w = 0; w < 16; ++w) s += red[w];
        out[0] = s / (float)BS;
    }
}

extern "C" void kernel_launch(void* const* d_in, const int* in_sizes, int n_in,
                              void* d_out, int out_size, void* d_ws, size_t ws_size,
                              hipStream_t stream) {
    const float* text = (const float*)d_in[0];
    const float* ctr  = (const float*)d_in[1];

    char* ws = (char*)d_ws;
    const size_t embBytes = (size_t)BS * DIM;   // fp8: 6,291,456 bytes each
    unsigned char* tq = (unsigned char*)ws;
    unsigned char* cq = (unsigned char*)(ws + embBytes);
    float* sim    = (float*)(ws + 2 * embBytes);
    float* rowsum = (float*)(ws + 2 * embBytes + BS * sizeof(float));
    float* colsum = (float*)(ws + 2 * embBytes + 2 * BS * sizeof(float));

    normalize_kernel<<<BS / 4, 256, 0, stream>>>(text, ctr, tq, cq, sim,
                                                 rowsum, colsum);

    gemm_lse_kernel<<<GRID, 512, 0, stream>>>(tq, cq, rowsum, colsum);

    finalize_kernel<<<1, 1024, 0, stream>>>(rowsum, colsum, sim, (float*)d_out);
}